// Round 1
// baseline (1415.082 us; speedup 1.0000x reference)
//
#include <hip/hip_runtime.h>

// Grouped SwiGLU MLP, MI355X gfx950.
// Round 1: bf16 MFMA pipeline.
//   cvt x/Wg/Wu/Wd fp32->bf16 into ws, then
//   gemm1: per-group dual GEMM (gate,up) 128x64 tile + fused silu -> hidden bf16
//   gemm2: per-group GEMM 128x128 tile -> fp32 out
// Staging via global_load_lds width=16 (wave-uniform base + lane*16), XOR-swizzled
// on the global side so ds_read_b128 is bank-conflict free.

#define GN 8
#define DN 1024
#define HN 2048
#define ON 1024
#define BN 8192  // rows per group (65536 / 8)

typedef __attribute__((ext_vector_type(8))) short short8;
typedef __attribute__((ext_vector_type(4))) float f32x4;
typedef __attribute__((ext_vector_type(4))) unsigned int u32x4;

__device__ __forceinline__ void async16(const void* g, void* l) {
  __builtin_amdgcn_global_load_lds(
      (const __attribute__((address_space(1))) void*)g,
      (__attribute__((address_space(3))) void*)l, 16, 0, 0);
}

__device__ __forceinline__ unsigned short f2bf(float f) {
  unsigned int u = __float_as_uint(f);
  u += 0x7FFFu + ((u >> 16) & 1u);  // round-to-nearest-even
  return (unsigned short)(u >> 16);
}

__global__ __launch_bounds__(256) void cvt_f32_bf16(
    const float* __restrict__ in, unsigned short* __restrict__ out, int n) {
  int t = blockIdx.x * 256 + threadIdx.x;
  int i = t * 8;
  if (i >= n) return;
  f32x4 a = *(const f32x4*)(in + i);
  f32x4 b = *(const f32x4*)(in + i + 4);
  u32x4 r;
  r.x = (unsigned)f2bf(a.x) | ((unsigned)f2bf(a.y) << 16);
  r.y = (unsigned)f2bf(a.z) | ((unsigned)f2bf(a.w) << 16);
  r.z = (unsigned)f2bf(b.x) | ((unsigned)f2bf(b.y) << 16);
  r.w = (unsigned)f2bf(b.z) | ((unsigned)f2bf(b.w) << 16);
  *(u32x4*)(out + i) = r;
}

// ---------------- Phase 1: gate/up dual GEMM + SwiGLU -> hidden bf16 ----------
// grid: (M/128=64, H/64=32, G=8), block 256 (4 waves, 2x2), BK=64.
__global__ __launch_bounds__(256, 2) void gemm1_swiglu(
    const unsigned short* __restrict__ Xb, const unsigned short* __restrict__ Wgb,
    const unsigned short* __restrict__ Wub, unsigned short* __restrict__ Hid) {
  const int g = blockIdx.z;
  const int m0 = blockIdx.x * 128;
  const int n0 = blockIdx.y * 64;
  const int tid = threadIdx.x;
  const int lane = tid & 63;
  const int w = tid >> 6;
  const int wm = w >> 1, wn = w & 1;

  __shared__ __align__(16) unsigned short lA[128 * 64];
  __shared__ __align__(16) unsigned short lG[64 * 64];
  __shared__ __align__(16) unsigned short lU[64 * 64];

  const int rl = lane >> 3;        // row-within-issue 0..7
  const int gc = (lane & 7) ^ rl;  // swizzled global 16B-chunk index

  // per-thread global staging base pointers (advance by k0 in the loop)
  const unsigned short* aptr[4];
#pragma unroll
  for (int i = 0; i < 4; ++i) {
    int r = w * 32 + i * 8 + rl;                        // A-tile local row
    aptr[i] = Xb + ((size_t)((m0 + r) * 8 + g)) * DN + gc * 8;
  }
  const unsigned short *gptr[2], *uptr[2];
#pragma unroll
  for (int i = 0; i < 2; ++i) {
    int r = w * 16 + i * 8 + rl;                        // B-tile local row
    gptr[i] = Wgb + ((size_t)(g * HN + n0 + r)) * DN + gc * 8;
    uptr[i] = Wub + ((size_t)(g * HN + n0 + r)) * DN + gc * 8;
  }

  f32x4 accg[4][2], accu[4][2];
#pragma unroll
  for (int mi = 0; mi < 4; ++mi)
#pragma unroll
    for (int ni = 0; ni < 2; ++ni) {
      accg[mi][ni] = (f32x4)(0.0f);
      accu[mi][ni] = (f32x4)(0.0f);
    }

  for (int k0 = 0; k0 < DN; k0 += 64) {
#pragma unroll
    for (int i = 0; i < 4; ++i)
      async16(aptr[i] + k0, &lA[(w * 32 + i * 8) * 64]);
#pragma unroll
    for (int i = 0; i < 2; ++i) {
      async16(gptr[i] + k0, &lG[(w * 16 + i * 8) * 64]);
      async16(uptr[i] + k0, &lU[(w * 16 + i * 8) * 64]);
    }
    __syncthreads();  // drains vmcnt (global_load_lds) before compute

#pragma unroll
    for (int ks = 0; ks < 2; ++ks) {
      const int c = (lane >> 4) + ks * 4;
      short8 af[4], bg[2], bu[2];
#pragma unroll
      for (int mi = 0; mi < 4; ++mi) {
        int r = wm * 64 + mi * 16 + (lane & 15);
        af[mi] = *(const short8*)&lA[r * 64 + ((c ^ (r & 7)) * 8)];
      }
#pragma unroll
      for (int ni = 0; ni < 2; ++ni) {
        int r = wn * 32 + ni * 16 + (lane & 15);
        int off = r * 64 + ((c ^ (r & 7)) * 8);
        bg[ni] = *(const short8*)&lG[off];
        bu[ni] = *(const short8*)&lU[off];
      }
#pragma unroll
      for (int mi = 0; mi < 4; ++mi)
#pragma unroll
        for (int ni = 0; ni < 2; ++ni) {
          accg[mi][ni] = __builtin_amdgcn_mfma_f32_16x16x32_bf16(
              af[mi], bg[ni], accg[mi][ni], 0, 0, 0);
          accu[mi][ni] = __builtin_amdgcn_mfma_f32_16x16x32_bf16(
              af[mi], bu[ni], accu[mi][ni], 0, 0, 0);
        }
    }
    __syncthreads();
  }

  // epilogue: silu(gate)*up -> bf16 hidden
  const int q = lane >> 4, cl = lane & 15;
#pragma unroll
  for (int mi = 0; mi < 4; ++mi)
#pragma unroll
    for (int ni = 0; ni < 2; ++ni) {
      int hcol = n0 + wn * 32 + ni * 16 + cl;
#pragma unroll
      for (int i = 0; i < 4; ++i) {
        int b = m0 + wm * 64 + mi * 16 + q * 4 + i;
        float gf = accg[mi][ni][i];
        float uf = accu[mi][ni][i];
        float hv = (gf / (1.0f + __expf(-gf))) * uf;
        Hid[((size_t)(b * 8 + g)) * HN + hcol] = f2bf(hv);
      }
    }
}

// ---------------- Phase 2: hidden @ Wd^T -> out fp32 -------------------------
// grid: (M/128=64, O/128=8, G=8), block 256 (4 waves, 2x2), BK=64.
__global__ __launch_bounds__(256, 2) void gemm2_down(
    const unsigned short* __restrict__ Hid, const unsigned short* __restrict__ Wdb,
    float* __restrict__ Out) {
  const int g = blockIdx.z;
  const int m0 = blockIdx.x * 128;
  const int n0 = blockIdx.y * 128;
  const int tid = threadIdx.x;
  const int lane = tid & 63;
  const int w = tid >> 6;
  const int wm = w >> 1, wn = w & 1;

  __shared__ __align__(16) unsigned short lA[128 * 64];
  __shared__ __align__(16) unsigned short lB[128 * 64];

  const int rl = lane >> 3;
  const int gc = (lane & 7) ^ rl;

  const unsigned short *aptr[4], *bptr[4];
#pragma unroll
  for (int i = 0; i < 4; ++i) {
    int r = w * 32 + i * 8 + rl;
    aptr[i] = Hid + ((size_t)((m0 + r) * 8 + g)) * HN + gc * 8;
    bptr[i] = Wdb + ((size_t)(g * ON + n0 + r)) * HN + gc * 8;
  }

  f32x4 acc[4][4];
#pragma unroll
  for (int mi = 0; mi < 4; ++mi)
#pragma unroll
    for (int ni = 0; ni < 4; ++ni) acc[mi][ni] = (f32x4)(0.0f);

  for (int k0 = 0; k0 < HN; k0 += 64) {
#pragma unroll
    for (int i = 0; i < 4; ++i) {
      async16(aptr[i] + k0, &lA[(w * 32 + i * 8) * 64]);
      async16(bptr[i] + k0, &lB[(w * 32 + i * 8) * 64]);
    }
    __syncthreads();

#pragma unroll
    for (int ks = 0; ks < 2; ++ks) {
      const int c = (lane >> 4) + ks * 4;
      short8 af[4], bf[4];
#pragma unroll
      for (int mi = 0; mi < 4; ++mi) {
        int r = wm * 64 + mi * 16 + (lane & 15);
        af[mi] = *(const short8*)&lA[r * 64 + ((c ^ (r & 7)) * 8)];
      }
#pragma unroll
      for (int ni = 0; ni < 4; ++ni) {
        int r = wn * 64 + ni * 16 + (lane & 15);
        bf[ni] = *(const short8*)&lB[r * 64 + ((c ^ (r & 7)) * 8)];
      }
#pragma unroll
      for (int mi = 0; mi < 4; ++mi)
#pragma unroll
        for (int ni = 0; ni < 4; ++ni)
          acc[mi][ni] = __builtin_amdgcn_mfma_f32_16x16x32_bf16(
              af[mi], bf[ni], acc[mi][ni], 0, 0, 0);
    }
    __syncthreads();
  }

  const int q = lane >> 4, cl = lane & 15;
#pragma unroll
  for (int mi = 0; mi < 4; ++mi)
#pragma unroll
    for (int ni = 0; ni < 4; ++ni) {
      int o = n0 + wn * 64 + ni * 16 + cl;
#pragma unroll
      for (int i = 0; i < 4; ++i) {
        int b = m0 + wm * 64 + mi * 16 + q * 4 + i;
        Out[((size_t)(b * 8 + g)) * ON + o] = acc[mi][ni][i];
      }
    }
}

extern "C" void kernel_launch(void* const* d_in, const int* in_sizes, int n_in,
                              void* d_out, int out_size, void* d_ws, size_t ws_size,
                              hipStream_t stream) {
  const float* x  = (const float*)d_in[0];   // [65536, 1024]
  const float* Wg = (const float*)d_in[1];   // [8, 2048, 1024]
  const float* Wu = (const float*)d_in[2];   // [8, 2048, 1024]
  const float* Wd = (const float*)d_in[3];   // [8, 1024, 2048]
  float* out = (float*)d_out;                // [65536, 1024]

  const int NX = 65536 * 1024;   // 67108864
  const int NW = GN * HN * DN;   // 16777216 (same count for Wd)

  unsigned short* xb = (unsigned short*)d_ws;
  unsigned short* wg = xb + (size_t)NX;
  unsigned short* wu = wg + (size_t)NW;
  unsigned short* wd = wu + (size_t)NW;
  unsigned short* hid = wd + (size_t)NW;     // [65536, 2048] bf16

  // fp32 -> bf16 conversions
  cvt_f32_bf16<<<NX / 8 / 256, 256, 0, stream>>>(x, xb, NX);
  cvt_f32_bf16<<<NW / 8 / 256, 256, 0, stream>>>(Wg, wg, NW);
  cvt_f32_bf16<<<NW / 8 / 256, 256, 0, stream>>>(Wu, wu, NW);
  cvt_f32_bf16<<<NW / 8 / 256, 256, 0, stream>>>(Wd, wd, NW);

  // phase 1: gate/up + SwiGLU -> hidden bf16
  gemm1_swiglu<<<dim3(BN / 128, HN / 64, GN), 256, 0, stream>>>(xb, wg, wu, hid);

  // phase 2: hidden @ Wd^T -> out fp32
  gemm2_down<<<dim3(BN / 128, ON / 128, GN), 256, 0, stream>>>(hid, wd, out);
}